// Round 7
// baseline (468.405 us; speedup 1.0000x reference)
//
#include <hip/hip_runtime.h>

#define NN 100000
#define NE 640000
#define HD 128
#define NG 512
#define NC 6
#define EPSV 1e-5f
#define OCT 12500   // NN/8 per dst-octant

typedef __bf16 bf16_t;
typedef bf16_t bf16x8 __attribute__((ext_vector_type(8)));
typedef float f32x4 __attribute__((ext_vector_type(4)));

__device__ __forceinline__ float b2f(unsigned int u16) {
    return __builtin_bit_cast(float, u16 << 16);
}
__device__ __forceinline__ unsigned short f2b(float f) {
    unsigned int u = __builtin_bit_cast(unsigned int, f);
    unsigned int r = (u + 0x7fffu + ((u >> 16) & 1u)) >> 16;
    return (unsigned short)r;
}

// ---------------- fused prep: x->bf16 cvt | weight transposes | octant count ----------------
// blocks [0,6250): cvt; [6250,6570): prepw; [6570,7530): count (XCD-local octants)
__global__ __launch_bounds__(256) void k_prep(
    const float* __restrict__ x, unsigned short* __restrict__ xb,
    const float* __restrict__ Wa, const float* __restrict__ Wb,
    const float* __restrict__ Wc, const float* __restrict__ Wd,
    const float* __restrict__ We, unsigned short* __restrict__ Wt,
    const int* __restrict__ dst, int* __restrict__ cnt)
{
    int bid = blockIdx.x;
    if (bid < 6250) {
        int i = bid * 256 + threadIdx.x;  // < 1,600,000
        float4 v0 = reinterpret_cast<const float4*>(x)[i * 2];
        float4 v1 = reinterpret_cast<const float4*>(x)[i * 2 + 1];
        unsigned short u[8] = {f2b(v0.x), f2b(v0.y), f2b(v0.z), f2b(v0.w),
                               f2b(v1.x), f2b(v1.y), f2b(v1.z), f2b(v1.w)};
        reinterpret_cast<uint4*>(xb)[i] = *reinterpret_cast<uint4*>(u);
    } else if (bid < 6570) {
        int i = (bid - 6250) * 256 + threadIdx.x;  // < 81920
        int w = i >> 14, r = i & 16383;
        int k = r >> 7, n = r & 127;
        const float* W = (w == 0) ? Wa : (w == 1) ? Wb : (w == 2) ? Wc : (w == 3) ? Wd : We;
        Wt[w * 16384 + n * HD + k] = f2b(W[k * HD + n]);
    } else {
        int q = bid - 6570;           // 0..959
        int oct = q & 7;              // consistent XCD per octant
        int widx = q >> 3;            // 0..119
        int lo = oct * OCT, hi = lo + OCT;
        for (int e = widx * 256 + threadIdx.x; e < NE; e += 120 * 256) {
            int d = dst[e];
            if (d >= lo && d < hi) atomicAdd(&cnt[d], 1);
        }
    }
}

// ---------------- single-block exclusive scan of cnt -> row_off ----------------
__global__ __launch_bounds__(1024) void k_scan_one(const int* __restrict__ cnt,
                                                   int* __restrict__ row_off) {
    __shared__ int sh[1024];
    const int CH = 98;  // 1024*98 >= 100000
    int t = threadIdx.x;
    int beg = t * CH, end = beg + CH;
    if (end > NN) end = NN;
    int s = 0;
    for (int i = beg; i < end; ++i) s += cnt[i];
    sh[t] = s;
    __syncthreads();
    for (int off = 1; off < 1024; off <<= 1) {
        int v = (t >= off) ? sh[t - off] : 0;
        __syncthreads();
        sh[t] += v;
        __syncthreads();
    }
    int run = t ? sh[t - 1] : 0;
    for (int i = beg; i < end; ++i) {
        row_off[i] = run;
        run += cnt[i];
    }
    if (t == 1023) row_off[NN] = NE;
}

// ---------------- octant-partitioned fill (XCD-local csr writes) ----------------
__global__ __launch_bounds__(256) void k_fill(const int* __restrict__ src,
                                              const int* __restrict__ dst,
                                              const int* __restrict__ row_off,
                                              int* __restrict__ cnt,
                                              int* __restrict__ csr) {
    int q = blockIdx.x;      // 0..959
    int oct = q & 7;
    int widx = q >> 3;
    int lo = oct * OCT, hi = lo + OCT;
    for (int e = widx * 256 + threadIdx.x; e < NE; e += 120 * 256) {
        int d = dst[e];
        if (d >= lo && d < hi) {
            int p = atomicSub(&cnt[d], 1);
            csr[row_off[d] + p - 1] = src[e];
        }
    }
}

// ---------------- mean aggregation: 8 neighbors in flight, 16B loads/lane ----------------
__global__ __launch_bounds__(256) void k_gather_b(const unsigned short* __restrict__ X,
                                                  const int* __restrict__ row_off,
                                                  const int* __restrict__ csr,
                                                  unsigned short* __restrict__ out) {
    int node = (blockIdx.x * blockDim.x + threadIdx.x) >> 6;
    int lane = threadIdx.x & 63;
    if (node >= NN) return;
    int beg = row_off[node], end = row_off[node + 1];
    int grp = lane >> 4;
    int sub = lane & 15;
    float accA[8] = {0.f, 0.f, 0.f, 0.f, 0.f, 0.f, 0.f, 0.f};
    float accB[8] = {0.f, 0.f, 0.f, 0.f, 0.f, 0.f, 0.f, 0.f};
    for (int j = beg; j < end; j += 8) {
        int jj0 = j + grp, jj1 = j + 4 + grp;
        bool ok0 = jj0 < end, ok1 = jj1 < end;
        int s0 = csr[ok0 ? jj0 : beg];
        int s1 = csr[ok1 ? jj1 : beg];
        uint4 v0 = *reinterpret_cast<const uint4*>(X + (size_t)s0 * HD + sub * 8);
        uint4 v1 = *reinterpret_cast<const uint4*>(X + (size_t)s1 * HD + sub * 8);
        if (ok0) {
            accA[0] += b2f(v0.x & 0xffffu); accA[1] += b2f(v0.x >> 16);
            accA[2] += b2f(v0.y & 0xffffu); accA[3] += b2f(v0.y >> 16);
            accA[4] += b2f(v0.z & 0xffffu); accA[5] += b2f(v0.z >> 16);
            accA[6] += b2f(v0.w & 0xffffu); accA[7] += b2f(v0.w >> 16);
        }
        if (ok1) {
            accB[0] += b2f(v1.x & 0xffffu); accB[1] += b2f(v1.x >> 16);
            accB[2] += b2f(v1.y & 0xffffu); accB[3] += b2f(v1.y >> 16);
            accB[4] += b2f(v1.z & 0xffffu); accB[5] += b2f(v1.z >> 16);
            accB[6] += b2f(v1.w & 0xffffu); accB[7] += b2f(v1.w >> 16);
        }
    }
#pragma unroll
    for (int k = 0; k < 8; ++k) {
        float a = accA[k] + accB[k];
        a += __shfl_xor(a, 16, 64);
        a += __shfl_xor(a, 32, 64);
        accA[k] = a;
    }
    if (grp == 0) {
        float inv = 1.f / fmaxf((float)(end - beg), 1.f);
        unsigned short u[8];
#pragma unroll
        for (int k = 0; k < 8; ++k) u[k] = f2b(accA[k] * inv);
        *reinterpret_cast<uint4*>(out + (size_t)node * HD + sub * 8) = *reinterpret_cast<uint4*>(u);
    }
}

// ---------------- MFMA dual-source GEMM, LDS-staged weights, 2-phase ----------------
__global__ __launch_bounds__(256) void mfma_dual(
    const unsigned short* __restrict__ A1, const unsigned short* __restrict__ W1t,
    const unsigned short* __restrict__ A2, const unsigned short* __restrict__ W2t,
    const float* __restrict__ bias, unsigned short* __restrict__ out, int M)
{
    __shared__ uint4 wlds[2048];  // 32 KB
    const int wid = threadIdx.x >> 6;
    const int lane = threadIdx.x & 63;
    const int lrow = lane & 15;
    const int lkg = lane >> 4;
    const int r0 = blockIdx.x * 128 + wid * 32;

    bf16x8 a[2][2][4];
#pragma unroll
    for (int s = 0; s < 2; ++s) {
        const unsigned short* Ap = s ? A2 : A1;
#pragma unroll
        for (int g = 0; g < 2; ++g) {
            int row = r0 + g * 16 + lrow;
            row = row < M ? row : M - 1;
            const unsigned short* p = Ap + (size_t)row * HD + lkg * 8;
#pragma unroll
            for (int ks = 0; ks < 4; ++ks)
                a[s][g][ks] = *reinterpret_cast<const bf16x8*>(p + ks * 32);
        }
    }

    f32x4 acc[2][8];
#pragma unroll
    for (int t = 0; t < 8; ++t) {
        float b = bias[t * 16 + lrow];
        acc[0][t] = (f32x4){b, b, b, b};
        acc[1][t] = (f32x4){b, b, b, b};
    }

    const char* ldsb = (const char*)wlds;
#pragma unroll
    for (int s = 0; s < 2; ++s) {
        const uint4* g4 = reinterpret_cast<const uint4*>(s ? W2t : W1t);
        if (s) __syncthreads();
        for (int i = threadIdx.x; i < 2048; i += 256) {
            int di = i ^ ((i >> 4) & 7);
            wlds[di] = g4[i];
        }
        __syncthreads();
#pragma unroll
        for (int ks = 0; ks < 4; ++ks) {
#pragma unroll
            for (int t = 0; t < 8; ++t) {
                int off = (lrow * 256 + lkg * 16 + t * 4096 + ks * 64) ^ ((lrow & 7) << 4);
                bf16x8 b = *reinterpret_cast<const bf16x8*>(ldsb + off);
                acc[0][t] = __builtin_amdgcn_mfma_f32_16x16x32_bf16(a[s][0][ks], b, acc[0][t], 0, 0, 0);
                acc[1][t] = __builtin_amdgcn_mfma_f32_16x16x32_bf16(a[s][1][ks], b, acc[1][t], 0, 0, 0);
            }
        }
    }

#pragma unroll
    for (int g = 0; g < 2; ++g)
#pragma unroll
        for (int t = 0; t < 8; ++t)
#pragma unroll
            for (int r = 0; r < 4; ++r) {
                int row = r0 + g * 16 + lkg * 4 + r;
                if (row < M) {
                    float v = fmaxf(acc[g][t][r], 0.f);
                    out[(size_t)row * HD + t * 16 + lrow] = f2b(v);
                }
            }
}

// ---------------- fused: a2 = softmax(tanh(h@Wc1+bc1) @ Wc2 + bc2), LDS weights ----------------
__global__ __launch_bounds__(256) void mfma_attn(
    const unsigned short* __restrict__ A1, const unsigned short* __restrict__ W1t,
    const float* __restrict__ bias, const float* __restrict__ Wc2,
    const float* __restrict__ bc2, float* __restrict__ a2, int M)
{
    __shared__ uint4 wlds[2048];
    const int wid = threadIdx.x >> 6;
    const int lane = threadIdx.x & 63;
    const int lrow = lane & 15;
    const int lkg = lane >> 4;
    const int r0 = blockIdx.x * 128 + wid * 32;

    bf16x8 a[2][4];
#pragma unroll
    for (int g = 0; g < 2; ++g) {
        int row = r0 + g * 16 + lrow;
        row = row < M ? row : M - 1;
        const unsigned short* p = A1 + (size_t)row * HD + lkg * 8;
#pragma unroll
        for (int ks = 0; ks < 4; ++ks)
            a[g][ks] = *reinterpret_cast<const bf16x8*>(p + ks * 32);
    }

    f32x4 acc[2][8];
#pragma unroll
    for (int t = 0; t < 8; ++t) {
        float b = bias[t * 16 + lrow];
        acc[0][t] = (f32x4){b, b, b, b};
        acc[1][t] = (f32x4){b, b, b, b};
    }

    const uint4* g4 = reinterpret_cast<const uint4*>(W1t);
    for (int i = threadIdx.x; i < 2048; i += 256) {
        int di = i ^ ((i >> 4) & 7);
        wlds[di] = g4[i];
    }
    __syncthreads();

    const char* ldsb = (const char*)wlds;
#pragma unroll
    for (int ks = 0; ks < 4; ++ks) {
#pragma unroll
        for (int t = 0; t < 8; ++t) {
            int off = (lrow * 256 + lkg * 16 + t * 4096 + ks * 64) ^ ((lrow & 7) << 4);
            bf16x8 b = *reinterpret_cast<const bf16x8*>(ldsb + off);
            acc[0][t] = __builtin_amdgcn_mfma_f32_16x16x32_bf16(a[0][ks], b, acc[0][t], 0, 0, 0);
            acc[1][t] = __builtin_amdgcn_mfma_f32_16x16x32_bf16(a[1][ks], b, acc[1][t], 0, 0, 0);
        }
    }

    float p0[2][4] = {{0.f, 0.f, 0.f, 0.f}, {0.f, 0.f, 0.f, 0.f}};
    float p1[2][4] = {{0.f, 0.f, 0.f, 0.f}, {0.f, 0.f, 0.f, 0.f}};
#pragma unroll
    for (int t = 0; t < 8; ++t) {
        float2 wv = reinterpret_cast<const float2*>(Wc2)[t * 16 + lrow];
#pragma unroll
        for (int g = 0; g < 2; ++g)
#pragma unroll
            for (int r = 0; r < 4; ++r) {
                float tv = tanhf(acc[g][t][r]);
                p0[g][r] = fmaf(tv, wv.x, p0[g][r]);
                p1[g][r] = fmaf(tv, wv.y, p1[g][r]);
            }
    }
#pragma unroll
    for (int off = 1; off < 16; off <<= 1) {
#pragma unroll
        for (int g = 0; g < 2; ++g)
#pragma unroll
            for (int r = 0; r < 4; ++r) {
                p0[g][r] += __shfl_xor(p0[g][r], off, 64);
                p1[g][r] += __shfl_xor(p1[g][r], off, 64);
            }
    }
    if (lrow == 0) {
        float B0 = bc2[0], B1 = bc2[1];
#pragma unroll
        for (int g = 0; g < 2; ++g)
#pragma unroll
            for (int r = 0; r < 4; ++r) {
                int row = r0 + g * 16 + lkg * 4 + r;
                if (row < M) {
                    float u0 = p0[g][r] + B0, u1 = p1[g][r] + B1;
                    float m = fmaxf(u0, u1);
                    float e0 = expf(u0 - m), e1 = expf(u1 - m);
                    float inv = 1.f / (e0 + e1);
                    reinterpret_cast<float2*>(a2)[row] = (float2){e0 * inv, e1 * inv};
                }
            }
    }
}

// ---------------- pos + colsum fused ----------------
__global__ __launch_bounds__(512) void k_pos(const unsigned short* __restrict__ h,
                                             const float* __restrict__ a2,
                                             const int* __restrict__ batch,
                                             float* __restrict__ pos_out,
                                             float* __restrict__ csum) {
    __shared__ float4 sh[8][64];
    int g = blockIdx.x;
    int lo = 0, hi = NN;
    while (lo < hi) { int m = (lo + hi) >> 1; if (batch[m] < g) lo = m + 1; else hi = m; }
    int beg = lo;
    hi = NN;
    while (lo < hi) { int m = (lo + hi) >> 1; if (batch[m] < g + 1) lo = m + 1; else hi = m; }
    int end = lo;
    int grp = threadIdx.x >> 6;
    int lane = threadIdx.x & 63;
    float4 acc = {0.f, 0.f, 0.f, 0.f};
    for (int i = beg + grp; i < end; i += 8) {
        float a = a2[i * 2];
        unsigned int v = *reinterpret_cast<const unsigned int*>(h + (size_t)i * HD + lane * 2);
        float f0 = b2f(v & 0xffffu), f1 = b2f(v >> 16);
        acc.x = fmaf(a, f0, acc.x);
        acc.y = fmaf(a, f1, acc.y);
        acc.z += f0;
        acc.w += f1;
    }
    sh[grp][lane] = acc;
    __syncthreads();
    if (threadIdx.x < 64) {
        float4 s = sh[0][lane];
#pragma unroll
        for (int k = 1; k < 8; ++k) {
            float4 t = sh[k][lane];
            s.x += t.x; s.y += t.y; s.z += t.z; s.w += t.w;
        }
        reinterpret_cast<float2*>(pos_out)[g * 64 + lane] = (float2){s.x, s.y};
        atomicAdd(&csum[lane * 2], s.z);
        atomicAdd(&csum[lane * 2 + 1], s.w);
    }
}

__global__ void k_gemb(const float* __restrict__ csum, float* __restrict__ out) {
    int i = blockIdx.x * 256 + threadIdx.x;  // 65536
    out[i] = csum[i & 127] * (1.f / (float)NN);
}

// ---------------- new_adj accumulation: LDS-staged atomics ----------------
__global__ __launch_bounds__(256) void k_adj(const int* __restrict__ src, const int* __restrict__ dst,
                                             const int* __restrict__ batch, const float* __restrict__ a2,
                                             float* __restrict__ adj) {
    __shared__ float sh[NG * 4];  // 8 KB
    for (int i = threadIdx.x; i < NG * 4; i += 256) sh[i] = 0.f;
    __syncthreads();
    for (int e = blockIdx.x * 256 + threadIdx.x; e < NE; e += gridDim.x * 256) {
        int s = src[e], d = dst[e];
        int bs = batch[s], bd = batch[d];
        if (bs != bd) continue;
        float a0s = a2[2 * s], a1s = a2[2 * s + 1];
        float a0d = a2[2 * d], a1d = a2[2 * d + 1];
        float* A = sh + bs * 4;
        atomicAdd(A + 0, a0s * a0d);
        atomicAdd(A + 1, a0s * a1d);
        atomicAdd(A + 2, a1s * a0d);
        atomicAdd(A + 3, a1s * a1d);
    }
    __syncthreads();
    for (int i = threadIdx.x; i < NG * 4; i += 256) {
        float v = sh[i];
        if (v != 0.f) atomicAdd(&adj[i], v);
    }
}

__global__ void k_penalty(const float* __restrict__ adj, float* __restrict__ out) {
    __shared__ float sh[512];
    int g = threadIdx.x;
    float x0 = adj[g * 4], x1 = adj[g * 4 + 1], x2 = adj[g * 4 + 2], x3 = adj[g * 4 + 3];
    float l0 = fabsf(x0) + fabsf(x1);
    float l1 = fabsf(x2) + fabsf(x3);
    float d0 = x0 / fmaxf(l0, EPSV);
    float d1 = x3 / fmaxf(l1, EPSV);
    sh[g] = 0.5f * ((d0 - 1.f) * (d0 - 1.f) + (d1 - 1.f) * (d1 - 1.f));
    __syncthreads();
    for (int off = 256; off >= 1; off >>= 1) {
        if (g < off) sh[g] += sh[g + off];
        __syncthreads();
    }
    if (g == 0) out[0] = sh[0] * (1.f / (float)NG);
}

// ---------------- fp32 head GEMM (512 rows): out = relu(A@W + b) ----------------
__global__ __launch_bounds__(256) void gemm_head(
    const float* __restrict__ A, const float* __restrict__ W,
    const float* __restrict__ bias, float* __restrict__ out, int M)
{
    const int tid = threadIdx.x;
    const int w = __builtin_amdgcn_readfirstlane(tid >> 6);
    const int lane = tid & 63;
    const int r0 = blockIdx.x * 32 + w * 8;
    if (r0 >= M) return;
    const int c0 = lane, c1 = lane + 64;
    float acc0[8], acc1[8];
    const float b0 = bias[c0], b1 = bias[c1];
#pragma unroll
    for (int r = 0; r < 8; ++r) { acc0[r] = b0; acc1[r] = b1; }
    const float* Ap = A + (size_t)r0 * HD;
    for (int k4 = 0; k4 < HD / 4; ++k4) {
        float4 a[8];
#pragma unroll
        for (int r = 0; r < 8; ++r)
            a[r] = *reinterpret_cast<const float4*>(Ap + r * HD + k4 * 4);
#pragma unroll
        for (int j = 0; j < 4; ++j) {
            const int k = k4 * 4 + j;
            const float w0 = W[k * HD + c0];
            const float w1 = W[k * HD + c1];
#pragma unroll
            for (int r = 0; r < 8; ++r) {
                const float av = (j == 0) ? a[r].x : (j == 1) ? a[r].y
                               : (j == 2) ? a[r].z : a[r].w;
                acc0[r] = fmaf(av, w0, acc0[r]);
                acc1[r] = fmaf(av, w1, acc1[r]);
            }
        }
    }
#pragma unroll
    for (int r = 0; r < 8; ++r) {
        out[(size_t)(r0 + r) * HD + c0] = fmaxf(acc0[r], 0.f);
        out[(size_t)(r0 + r) * HD + c1] = fmaxf(acc1[r], 0.f);
    }
}

// ---------------- final head: logits + log_softmax ----------------
__global__ void k_head(const float* __restrict__ z, const float* __restrict__ Wl2,
                       const float* __restrict__ bl2, float* __restrict__ out0) {
    int g = blockIdx.x * blockDim.x + threadIdx.x;
    if (g >= NG) return;
    float l[NC];
#pragma unroll
    for (int c = 0; c < NC; ++c) l[c] = bl2[c];
    for (int k = 0; k < HD; ++k) {
        float zv = z[(size_t)g * HD + k];
#pragma unroll
        for (int c = 0; c < NC; ++c) l[c] = fmaf(zv, Wl2[k * NC + c], l[c]);
    }
    float m = l[0];
#pragma unroll
    for (int c = 1; c < NC; ++c) m = fmaxf(m, l[c]);
    float sum = 0.f;
#pragma unroll
    for (int c = 0; c < NC; ++c) sum += expf(l[c] - m);
    float lse = m + logf(sum);
#pragma unroll
    for (int c = 0; c < NC; ++c) out0[g * NC + c] = l[c] - lse;
}

extern "C" void kernel_launch(void* const* d_in, const int* in_sizes, int n_in,
                              void* d_out, int out_size, void* d_ws, size_t ws_size,
                              hipStream_t stream) {
    const float* x   = (const float*)d_in[0];
    const int*   ei  = (const int*)d_in[1];
    const int*   src = ei;
    const int*   dst = ei + NE;
    const int*   batch = (const int*)d_in[2];
    const float* W1l = (const float*)d_in[4];
    const float* b1l = (const float*)d_in[5];
    const float* W1r = (const float*)d_in[6];
    const float* W2l = (const float*)d_in[7];
    const float* b2l = (const float*)d_in[8];
    const float* W2r = (const float*)d_in[9];
    const float* Wc1 = (const float*)d_in[10];
    const float* bc1 = (const float*)d_in[11];
    const float* Wc2 = (const float*)d_in[12];
    const float* bc2 = (const float*)d_in[13];
    const float* Wl1 = (const float*)d_in[14];
    const float* bl1 = (const float*)d_in[15];
    const float* Wl2 = (const float*)d_in[16];
    const float* bl2 = (const float*)d_in[17];

    char* ws = (char*)d_ws;
    const size_t BB = (size_t)NN * HD * 2;  // 25,600,000 (bf16 buffer)
    unsigned short* xb   = (unsigned short*)(ws);
    unsigned short* bufA = (unsigned short*)(ws + BB);
    unsigned short* bufB = (unsigned short*)(ws + 2 * BB);
    size_t O = 3 * BB;  // 76,800,000
    // zeroed region (single memset): cnt | adj | csum
    int*   cnt     = (int*)(ws + O);                 // 400000 B
    float* adj     = (float*)(ws + O + 400000);      // 8192 B
    float* csum    = (float*)(ws + O + 408192);      // 512 B
    // non-zeroed scratch
    int*   row_off = (int*)(ws + O + 408704);        // 400064 B
    int*   csr     = (int*)(ws + O + 808768);        // 2560000 B
    float* a2      = (float*)(ws + O + 3368768);     // 800000 B
    float* zbuf    = (float*)(ws + O + 4168768);     // 262144 B
    unsigned short* w1lt = (unsigned short*)(ws + O + 4430912);  // 5*32768 B
    unsigned short* w1rt = w1lt + 16384;
    unsigned short* w2lt = w1rt + 16384;
    unsigned short* w2rt = w2lt + 16384;
    unsigned short* wc1t = w2rt + 16384;

    float* out0 = (float*)d_out;     // 512*6
    float* pos  = out0 + NG * NC;    // 512*128
    float* gemb = pos + NG * HD;     // 512*128
    float* pen  = gemb + NG * HD;    // 1

    hipMemsetAsync(ws + O, 0, 408704, stream);  // cnt+adj+csum

    // fused prep: cvt | weight transposes | octant count
    k_prep<<<7530, 256, 0, stream>>>(x, xb, W1l, W1r, W2l, W2r, Wc1, w1lt, dst, cnt);
    // scan (1 block)
    k_scan_one<<<1, 1024, 0, stream>>>(cnt, row_off);
    // octant fill (consumes cnt via count-down)
    k_fill<<<960, 256, 0, stream>>>(src, dst, row_off, cnt, csr);

    const int GEMM_GRID = (NN + 127) / 128;  // 782
    // Layer 1: h1 = relu(mean@W1l + xb@W1r + b1l) -> bufB
    k_gather_b<<<NN / 4, 256, 0, stream>>>(xb, row_off, csr, bufA);
    mfma_dual<<<GEMM_GRID, 256, 0, stream>>>(bufA, w1lt, xb, w1rt, b1l, bufB, NN);
    // Layer 2: h2 = relu(mean@W2l + h1@W2r + b2l) -> xb
    k_gather_b<<<NN / 4, 256, 0, stream>>>(bufB, row_off, csr, bufA);
    mfma_dual<<<GEMM_GRID, 256, 0, stream>>>(bufA, w2lt, bufB, w2rt, b2l, xb, NN);
    // fused: a = softmax(tanh(h2@Wc1+bc1)@Wc2 + bc2)
    mfma_attn<<<GEMM_GRID, 256, 0, stream>>>(xb, wc1t, bc1, Wc2, bc2, a2, NN);
    // pos + colsum fused
    k_pos<<<NG, 512, 0, stream>>>(xb, a2, batch, pos, csum);
    // graph_emb
    k_gemb<<<NG * HD / 256, 256, 0, stream>>>(csum, gemb);
    // new_adj + penalty
    k_adj<<<120, 256, 0, stream>>>(src, dst, batch, a2, adj);
    k_penalty<<<1, 512, 0, stream>>>(adj, pen);
    // head
    gemm_head<<<NG / 32, 256, 0, stream>>>(pos, Wl1, bl1, zbuf, NG);
    k_head<<<2, 256, 0, stream>>>(zbuf, Wl2, bl2, out0);
}

// Round 8
// 315.973 us; speedup vs baseline: 1.4824x; 1.4824x over previous
//
#include <hip/hip_runtime.h>

#define NN 100000
#define NE 640000
#define HD 128
#define NG 512
#define NC 6
#define EPSV 1e-5f
#define OCT 12500   // NN/8 per dst-octant

typedef __bf16 bf16_t;
typedef bf16_t bf16x8 __attribute__((ext_vector_type(8)));
typedef float f32x4 __attribute__((ext_vector_type(4)));

__device__ __forceinline__ float b2f(unsigned int u16) {
    return __builtin_bit_cast(float, u16 << 16);
}
__device__ __forceinline__ unsigned short f2b(float f) {
    unsigned int u = __builtin_bit_cast(unsigned int, f);
    unsigned int r = (u + 0x7fffu + ((u >> 16) & 1u)) >> 16;
    return (unsigned short)r;
}

// ---------------- fused prep: x->bf16 cvt | weight transposes | octant count ----------------
// blocks [0,6250): cvt; [6250,6570): prepw; [6570,7530): count (XCD-local octants)
__global__ __launch_bounds__(256) void k_prep(
    const float* __restrict__ x, unsigned short* __restrict__ xb,
    const float* __restrict__ Wa, const float* __restrict__ Wb,
    const float* __restrict__ Wc, const float* __restrict__ Wd,
    const float* __restrict__ We, unsigned short* __restrict__ Wt,
    const int* __restrict__ dst, int* __restrict__ cnt)
{
    int bid = blockIdx.x;
    if (bid < 6250) {
        int i = bid * 256 + threadIdx.x;  // < 1,600,000
        float4 v0 = reinterpret_cast<const float4*>(x)[i * 2];
        float4 v1 = reinterpret_cast<const float4*>(x)[i * 2 + 1];
        unsigned short u[8] = {f2b(v0.x), f2b(v0.y), f2b(v0.z), f2b(v0.w),
                               f2b(v1.x), f2b(v1.y), f2b(v1.z), f2b(v1.w)};
        reinterpret_cast<uint4*>(xb)[i] = *reinterpret_cast<uint4*>(u);
    } else if (bid < 6570) {
        int i = (bid - 6250) * 256 + threadIdx.x;  // < 81920
        int w = i >> 14, r = i & 16383;
        int k = r >> 7, n = r & 127;
        const float* W = (w == 0) ? Wa : (w == 1) ? Wb : (w == 2) ? Wc : (w == 3) ? Wd : We;
        Wt[w * 16384 + n * HD + k] = f2b(W[k * HD + n]);
    } else {
        int q = bid - 6570;           // 0..959
        int oct = q & 7;              // consistent XCD per octant
        int widx = q >> 3;            // 0..119
        int lo = oct * OCT, hi = lo + OCT;
        for (int e = widx * 256 + threadIdx.x; e < NE; e += 120 * 256) {
            int d = dst[e];
            if (d >= lo && d < hi) atomicAdd(&cnt[d], 1);
        }
    }
}

// ---------------- hierarchical scan (3 kernels, parallel) ----------------
__global__ void k_scan1(const int* __restrict__ cnt, int* __restrict__ excl,
                        int* __restrict__ bsum, int n) {
    __shared__ int sh[256];
    int i = blockIdx.x * 256 + threadIdx.x;
    int v = (i < n) ? cnt[i] : 0;
    sh[threadIdx.x] = v;
    __syncthreads();
    for (int off = 1; off < 256; off <<= 1) {
        int t = (threadIdx.x >= off) ? sh[threadIdx.x - off] : 0;
        __syncthreads();
        sh[threadIdx.x] += t;
        __syncthreads();
    }
    if (i < n) excl[i] = sh[threadIdx.x] - v;
    if (threadIdx.x == 255) bsum[blockIdx.x] = sh[255];
}

__global__ void k_scan2(int* bsum, int nb) {
    __shared__ int sh[512];
    int t = threadIdx.x;
    sh[t] = (t < nb) ? bsum[t] : 0;
    __syncthreads();
    for (int off = 1; off < 512; off <<= 1) {
        int v = (t >= off) ? sh[t - off] : 0;
        __syncthreads();
        sh[t] += v;
        __syncthreads();
    }
    if (t < nb) bsum[t] = sh[t];
}

__global__ void k_scan3(const int* __restrict__ excl, const int* __restrict__ bsum,
                        int* __restrict__ row_off, int n) {
    int i = blockIdx.x * 256 + threadIdx.x;
    if (i < n) row_off[i] = excl[i] + (blockIdx.x ? bsum[blockIdx.x - 1] : 0);
    if (i == 0) row_off[n] = NE;
}

// ---------------- octant-partitioned fill (XCD-local csr writes) ----------------
__global__ __launch_bounds__(256) void k_fill(const int* __restrict__ src,
                                              const int* __restrict__ dst,
                                              const int* __restrict__ row_off,
                                              int* __restrict__ cnt,
                                              int* __restrict__ csr) {
    int q = blockIdx.x;      // 0..959
    int oct = q & 7;
    int widx = q >> 3;
    int lo = oct * OCT, hi = lo + OCT;
    for (int e = widx * 256 + threadIdx.x; e < NE; e += 120 * 256) {
        int d = dst[e];
        if (d >= lo && d < hi) {
            int p = atomicSub(&cnt[d], 1);
            csr[row_off[d] + p - 1] = src[e];
        }
    }
}

// ---------------- mean aggregation: 8 neighbors in flight, 16B loads/lane ----------------
__global__ __launch_bounds__(256) void k_gather_b(const unsigned short* __restrict__ X,
                                                  const int* __restrict__ row_off,
                                                  const int* __restrict__ csr,
                                                  unsigned short* __restrict__ out) {
    int node = (blockIdx.x * blockDim.x + threadIdx.x) >> 6;
    int lane = threadIdx.x & 63;
    if (node >= NN) return;
    int beg = row_off[node], end = row_off[node + 1];
    int grp = lane >> 4;
    int sub = lane & 15;
    float accA[8] = {0.f, 0.f, 0.f, 0.f, 0.f, 0.f, 0.f, 0.f};
    float accB[8] = {0.f, 0.f, 0.f, 0.f, 0.f, 0.f, 0.f, 0.f};
    for (int j = beg; j < end; j += 8) {
        int jj0 = j + grp, jj1 = j + 4 + grp;
        bool ok0 = jj0 < end, ok1 = jj1 < end;
        int s0 = csr[ok0 ? jj0 : beg];
        int s1 = csr[ok1 ? jj1 : beg];
        uint4 v0 = *reinterpret_cast<const uint4*>(X + (size_t)s0 * HD + sub * 8);
        uint4 v1 = *reinterpret_cast<const uint4*>(X + (size_t)s1 * HD + sub * 8);
        if (ok0) {
            accA[0] += b2f(v0.x & 0xffffu); accA[1] += b2f(v0.x >> 16);
            accA[2] += b2f(v0.y & 0xffffu); accA[3] += b2f(v0.y >> 16);
            accA[4] += b2f(v0.z & 0xffffu); accA[5] += b2f(v0.z >> 16);
            accA[6] += b2f(v0.w & 0xffffu); accA[7] += b2f(v0.w >> 16);
        }
        if (ok1) {
            accB[0] += b2f(v1.x & 0xffffu); accB[1] += b2f(v1.x >> 16);
            accB[2] += b2f(v1.y & 0xffffu); accB[3] += b2f(v1.y >> 16);
            accB[4] += b2f(v1.z & 0xffffu); accB[5] += b2f(v1.z >> 16);
            accB[6] += b2f(v1.w & 0xffffu); accB[7] += b2f(v1.w >> 16);
        }
    }
#pragma unroll
    for (int k = 0; k < 8; ++k) {
        float a = accA[k] + accB[k];
        a += __shfl_xor(a, 16, 64);
        a += __shfl_xor(a, 32, 64);
        accA[k] = a;
    }
    if (grp == 0) {
        float inv = 1.f / fmaxf((float)(end - beg), 1.f);
        unsigned short u[8];
#pragma unroll
        for (int k = 0; k < 8; ++k) u[k] = f2b(accA[k] * inv);
        *reinterpret_cast<uint4*>(out + (size_t)node * HD + sub * 8) = *reinterpret_cast<uint4*>(u);
    }
}

// ---------------- MFMA dual-source GEMM, LDS-staged weights, 2-phase ----------------
__global__ __launch_bounds__(256) void mfma_dual(
    const unsigned short* __restrict__ A1, const unsigned short* __restrict__ W1t,
    const unsigned short* __restrict__ A2, const unsigned short* __restrict__ W2t,
    const float* __restrict__ bias, unsigned short* __restrict__ out, int M)
{
    __shared__ uint4 wlds[2048];  // 32 KB
    const int wid = threadIdx.x >> 6;
    const int lane = threadIdx.x & 63;
    const int lrow = lane & 15;
    const int lkg = lane >> 4;
    const int r0 = blockIdx.x * 128 + wid * 32;

    bf16x8 a[2][2][4];
#pragma unroll
    for (int s = 0; s < 2; ++s) {
        const unsigned short* Ap = s ? A2 : A1;
#pragma unroll
        for (int g = 0; g < 2; ++g) {
            int row = r0 + g * 16 + lrow;
            row = row < M ? row : M - 1;
            const unsigned short* p = Ap + (size_t)row * HD + lkg * 8;
#pragma unroll
            for (int ks = 0; ks < 4; ++ks)
                a[s][g][ks] = *reinterpret_cast<const bf16x8*>(p + ks * 32);
        }
    }

    f32x4 acc[2][8];
#pragma unroll
    for (int t = 0; t < 8; ++t) {
        float b = bias[t * 16 + lrow];
        acc[0][t] = (f32x4){b, b, b, b};
        acc[1][t] = (f32x4){b, b, b, b};
    }

    const char* ldsb = (const char*)wlds;
#pragma unroll
    for (int s = 0; s < 2; ++s) {
        const uint4* g4 = reinterpret_cast<const uint4*>(s ? W2t : W1t);
        if (s) __syncthreads();
        for (int i = threadIdx.x; i < 2048; i += 256) {
            int di = i ^ ((i >> 4) & 7);
            wlds[di] = g4[i];
        }
        __syncthreads();
#pragma unroll
        for (int ks = 0; ks < 4; ++ks) {
#pragma unroll
            for (int t = 0; t < 8; ++t) {
                int off = (lrow * 256 + lkg * 16 + t * 4096 + ks * 64) ^ ((lrow & 7) << 4);
                bf16x8 b = *reinterpret_cast<const bf16x8*>(ldsb + off);
                acc[0][t] = __builtin_amdgcn_mfma_f32_16x16x32_bf16(a[s][0][ks], b, acc[0][t], 0, 0, 0);
                acc[1][t] = __builtin_amdgcn_mfma_f32_16x16x32_bf16(a[s][1][ks], b, acc[1][t], 0, 0, 0);
            }
        }
    }

#pragma unroll
    for (int g = 0; g < 2; ++g)
#pragma unroll
        for (int t = 0; t < 8; ++t)
#pragma unroll
            for (int r = 0; r < 4; ++r) {
                int row = r0 + g * 16 + lkg * 4 + r;
                if (row < M) {
                    float v = fmaxf(acc[g][t][r], 0.f);
                    out[(size_t)row * HD + t * 16 + lrow] = f2b(v);
                }
            }
}

// ---------------- fused: a2 = softmax(tanh(h@Wc1+bc1) @ Wc2 + bc2), LDS weights ----------------
__global__ __launch_bounds__(256) void mfma_attn(
    const unsigned short* __restrict__ A1, const unsigned short* __restrict__ W1t,
    const float* __restrict__ bias, const float* __restrict__ Wc2,
    const float* __restrict__ bc2, float* __restrict__ a2, int M)
{
    __shared__ uint4 wlds[2048];
    const int wid = threadIdx.x >> 6;
    const int lane = threadIdx.x & 63;
    const int lrow = lane & 15;
    const int lkg = lane >> 4;
    const int r0 = blockIdx.x * 128 + wid * 32;

    bf16x8 a[2][4];
#pragma unroll
    for (int g = 0; g < 2; ++g) {
        int row = r0 + g * 16 + lrow;
        row = row < M ? row : M - 1;
        const unsigned short* p = A1 + (size_t)row * HD + lkg * 8;
#pragma unroll
        for (int ks = 0; ks < 4; ++ks)
            a[g][ks] = *reinterpret_cast<const bf16x8*>(p + ks * 32);
    }

    f32x4 acc[2][8];
#pragma unroll
    for (int t = 0; t < 8; ++t) {
        float b = bias[t * 16 + lrow];
        acc[0][t] = (f32x4){b, b, b, b};
        acc[1][t] = (f32x4){b, b, b, b};
    }

    const uint4* g4 = reinterpret_cast<const uint4*>(W1t);
    for (int i = threadIdx.x; i < 2048; i += 256) {
        int di = i ^ ((i >> 4) & 7);
        wlds[di] = g4[i];
    }
    __syncthreads();

    const char* ldsb = (const char*)wlds;
#pragma unroll
    for (int ks = 0; ks < 4; ++ks) {
#pragma unroll
        for (int t = 0; t < 8; ++t) {
            int off = (lrow * 256 + lkg * 16 + t * 4096 + ks * 64) ^ ((lrow & 7) << 4);
            bf16x8 b = *reinterpret_cast<const bf16x8*>(ldsb + off);
            acc[0][t] = __builtin_amdgcn_mfma_f32_16x16x32_bf16(a[0][ks], b, acc[0][t], 0, 0, 0);
            acc[1][t] = __builtin_amdgcn_mfma_f32_16x16x32_bf16(a[1][ks], b, acc[1][t], 0, 0, 0);
        }
    }

    float p0[2][4] = {{0.f, 0.f, 0.f, 0.f}, {0.f, 0.f, 0.f, 0.f}};
    float p1[2][4] = {{0.f, 0.f, 0.f, 0.f}, {0.f, 0.f, 0.f, 0.f}};
#pragma unroll
    for (int t = 0; t < 8; ++t) {
        float2 wv = reinterpret_cast<const float2*>(Wc2)[t * 16 + lrow];
#pragma unroll
        for (int g = 0; g < 2; ++g)
#pragma unroll
            for (int r = 0; r < 4; ++r) {
                float tv = tanhf(acc[g][t][r]);
                p0[g][r] = fmaf(tv, wv.x, p0[g][r]);
                p1[g][r] = fmaf(tv, wv.y, p1[g][r]);
            }
    }
#pragma unroll
    for (int off = 1; off < 16; off <<= 1) {
#pragma unroll
        for (int g = 0; g < 2; ++g)
#pragma unroll
            for (int r = 0; r < 4; ++r) {
                p0[g][r] += __shfl_xor(p0[g][r], off, 64);
                p1[g][r] += __shfl_xor(p1[g][r], off, 64);
            }
    }
    if (lrow == 0) {
        float B0 = bc2[0], B1 = bc2[1];
#pragma unroll
        for (int g = 0; g < 2; ++g)
#pragma unroll
            for (int r = 0; r < 4; ++r) {
                int row = r0 + g * 16 + lkg * 4 + r;
                if (row < M) {
                    float u0 = p0[g][r] + B0, u1 = p1[g][r] + B1;
                    float m = fmaxf(u0, u1);
                    float e0 = expf(u0 - m), e1 = expf(u1 - m);
                    float inv = 1.f / (e0 + e1);
                    reinterpret_cast<float2*>(a2)[row] = (float2){e0 * inv, e1 * inv};
                }
            }
    }
}

// ---------------- pos + colsum fused ----------------
__global__ __launch_bounds__(512) void k_pos(const unsigned short* __restrict__ h,
                                             const float* __restrict__ a2,
                                             const int* __restrict__ batch,
                                             float* __restrict__ pos_out,
                                             float* __restrict__ csum) {
    __shared__ float4 sh[8][64];
    int g = blockIdx.x;
    int lo = 0, hi = NN;
    while (lo < hi) { int m = (lo + hi) >> 1; if (batch[m] < g) lo = m + 1; else hi = m; }
    int beg = lo;
    hi = NN;
    while (lo < hi) { int m = (lo + hi) >> 1; if (batch[m] < g + 1) lo = m + 1; else hi = m; }
    int end = lo;
    int grp = threadIdx.x >> 6;
    int lane = threadIdx.x & 63;
    float4 acc = {0.f, 0.f, 0.f, 0.f};
    for (int i = beg + grp; i < end; i += 8) {
        float a = a2[i * 2];
        unsigned int v = *reinterpret_cast<const unsigned int*>(h + (size_t)i * HD + lane * 2);
        float f0 = b2f(v & 0xffffu), f1 = b2f(v >> 16);
        acc.x = fmaf(a, f0, acc.x);
        acc.y = fmaf(a, f1, acc.y);
        acc.z += f0;
        acc.w += f1;
    }
    sh[grp][lane] = acc;
    __syncthreads();
    if (threadIdx.x < 64) {
        float4 s = sh[0][lane];
#pragma unroll
        for (int k = 1; k < 8; ++k) {
            float4 t = sh[k][lane];
            s.x += t.x; s.y += t.y; s.z += t.z; s.w += t.w;
        }
        reinterpret_cast<float2*>(pos_out)[g * 64 + lane] = (float2){s.x, s.y};
        atomicAdd(&csum[lane * 2], s.z);
        atomicAdd(&csum[lane * 2 + 1], s.w);
    }
}

__global__ void k_gemb(const float* __restrict__ csum, float* __restrict__ out) {
    int i = blockIdx.x * 256 + threadIdx.x;  // 65536
    out[i] = csum[i & 127] * (1.f / (float)NN);
}

// ---------------- new_adj accumulation: LDS-staged atomics ----------------
__global__ __launch_bounds__(256) void k_adj(const int* __restrict__ src, const int* __restrict__ dst,
                                             const int* __restrict__ batch, const float* __restrict__ a2,
                                             float* __restrict__ adj) {
    __shared__ float sh[NG * 4];  // 8 KB
    for (int i = threadIdx.x; i < NG * 4; i += 256) sh[i] = 0.f;
    __syncthreads();
    for (int e = blockIdx.x * 256 + threadIdx.x; e < NE; e += gridDim.x * 256) {
        int s = src[e], d = dst[e];
        int bs = batch[s], bd = batch[d];
        if (bs != bd) continue;
        float a0s = a2[2 * s], a1s = a2[2 * s + 1];
        float a0d = a2[2 * d], a1d = a2[2 * d + 1];
        float* A = sh + bs * 4;
        atomicAdd(A + 0, a0s * a0d);
        atomicAdd(A + 1, a0s * a1d);
        atomicAdd(A + 2, a1s * a0d);
        atomicAdd(A + 3, a1s * a1d);
    }
    __syncthreads();
    for (int i = threadIdx.x; i < NG * 4; i += 256) {
        float v = sh[i];
        if (v != 0.f) atomicAdd(&adj[i], v);
    }
}

__global__ void k_penalty(const float* __restrict__ adj, float* __restrict__ out) {
    __shared__ float sh[512];
    int g = threadIdx.x;
    float x0 = adj[g * 4], x1 = adj[g * 4 + 1], x2 = adj[g * 4 + 2], x3 = adj[g * 4 + 3];
    float l0 = fabsf(x0) + fabsf(x1);
    float l1 = fabsf(x2) + fabsf(x3);
    float d0 = x0 / fmaxf(l0, EPSV);
    float d1 = x3 / fmaxf(l1, EPSV);
    sh[g] = 0.5f * ((d0 - 1.f) * (d0 - 1.f) + (d1 - 1.f) * (d1 - 1.f));
    __syncthreads();
    for (int off = 256; off >= 1; off >>= 1) {
        if (g < off) sh[g] += sh[g + off];
        __syncthreads();
    }
    if (g == 0) out[0] = sh[0] * (1.f / (float)NG);
}

// ---------------- fp32 head GEMM (512 rows): out = relu(A@W + b) ----------------
__global__ __launch_bounds__(256) void gemm_head(
    const float* __restrict__ A, const float* __restrict__ W,
    const float* __restrict__ bias, float* __restrict__ out, int M)
{
    const int tid = threadIdx.x;
    const int w = __builtin_amdgcn_readfirstlane(tid >> 6);
    const int lane = tid & 63;
    const int r0 = blockIdx.x * 32 + w * 8;
    if (r0 >= M) return;
    const int c0 = lane, c1 = lane + 64;
    float acc0[8], acc1[8];
    const float b0 = bias[c0], b1 = bias[c1];
#pragma unroll
    for (int r = 0; r < 8; ++r) { acc0[r] = b0; acc1[r] = b1; }
    const float* Ap = A + (size_t)r0 * HD;
    for (int k4 = 0; k4 < HD / 4; ++k4) {
        float4 a[8];
#pragma unroll
        for (int r = 0; r < 8; ++r)
            a[r] = *reinterpret_cast<const float4*>(Ap + r * HD + k4 * 4);
#pragma unroll
        for (int j = 0; j < 4; ++j) {
            const int k = k4 * 4 + j;
            const float w0 = W[k * HD + c0];
            const float w1 = W[k * HD + c1];
#pragma unroll
            for (int r = 0; r < 8; ++r) {
                const float av = (j == 0) ? a[r].x : (j == 1) ? a[r].y
                               : (j == 2) ? a[r].z : a[r].w;
                acc0[r] = fmaf(av, w0, acc0[r]);
                acc1[r] = fmaf(av, w1, acc1[r]);
            }
        }
    }
#pragma unroll
    for (int r = 0; r < 8; ++r) {
        out[(size_t)(r0 + r) * HD + c0] = fmaxf(acc0[r], 0.f);
        out[(size_t)(r0 + r) * HD + c1] = fmaxf(acc1[r], 0.f);
    }
}

// ---------------- final head: logits + log_softmax ----------------
__global__ void k_head(const float* __restrict__ z, const float* __restrict__ Wl2,
                       const float* __restrict__ bl2, float* __restrict__ out0) {
    int g = blockIdx.x * blockDim.x + threadIdx.x;
    if (g >= NG) return;
    float l[NC];
#pragma unroll
    for (int c = 0; c < NC; ++c) l[c] = bl2[c];
    for (int k = 0; k < HD; ++k) {
        float zv = z[(size_t)g * HD + k];
#pragma unroll
        for (int c = 0; c < NC; ++c) l[c] = fmaf(zv, Wl2[k * NC + c], l[c]);
    }
    float m = l[0];
#pragma unroll
    for (int c = 1; c < NC; ++c) m = fmaxf(m, l[c]);
    float sum = 0.f;
#pragma unroll
    for (int c = 0; c < NC; ++c) sum += expf(l[c] - m);
    float lse = m + logf(sum);
#pragma unroll
    for (int c = 0; c < NC; ++c) out0[g * NC + c] = l[c] - lse;
}

extern "C" void kernel_launch(void* const* d_in, const int* in_sizes, int n_in,
                              void* d_out, int out_size, void* d_ws, size_t ws_size,
                              hipStream_t stream) {
    const float* x   = (const float*)d_in[0];
    const int*   ei  = (const int*)d_in[1];
    const int*   src = ei;
    const int*   dst = ei + NE;
    const int*   batch = (const int*)d_in[2];
    const float* W1l = (const float*)d_in[4];
    const float* b1l = (const float*)d_in[5];
    const float* W1r = (const float*)d_in[6];
    const float* W2l = (const float*)d_in[7];
    const float* b2l = (const float*)d_in[8];
    const float* W2r = (const float*)d_in[9];
    const float* Wc1 = (const float*)d_in[10];
    const float* bc1 = (const float*)d_in[11];
    const float* Wc2 = (const float*)d_in[12];
    const float* bc2 = (const float*)d_in[13];
    const float* Wl1 = (const float*)d_in[14];
    const float* bl1 = (const float*)d_in[15];
    const float* Wl2 = (const float*)d_in[16];
    const float* bl2 = (const float*)d_in[17];

    char* ws = (char*)d_ws;
    const size_t BB = (size_t)NN * HD * 2;  // 25,600,000 (bf16 buffer)
    unsigned short* xb   = (unsigned short*)(ws);
    unsigned short* bufA = (unsigned short*)(ws + BB);
    unsigned short* bufB = (unsigned short*)(ws + 2 * BB);
    size_t O = 3 * BB;  // 76,800,000
    // zeroed region (single memset): cnt | adj | csum
    int*   cnt     = (int*)(ws + O);                 // 400000 B
    float* adj     = (float*)(ws + O + 400000);      // 8192 B
    float* csum    = (float*)(ws + O + 408192);      // 512 B
    // non-zeroed scratch
    int*   row_off = (int*)(ws + O + 408704);        // 400064 B
    int*   excl    = (int*)(ws + O + 808768);        // 400000 B
    int*   bsum    = (int*)(ws + O + 1208768);       // 4096 B
    int*   csr     = (int*)(ws + O + 1212864);       // 2560000 B
    float* a2      = (float*)(ws + O + 3772864);     // 800000 B
    float* zbuf    = (float*)(ws + O + 4572864);     // 262144 B
    unsigned short* w1lt = (unsigned short*)(ws + O + 4835008);  // 5*32768 B
    unsigned short* w1rt = w1lt + 16384;
    unsigned short* w2lt = w1rt + 16384;
    unsigned short* w2rt = w2lt + 16384;
    unsigned short* wc1t = w2rt + 16384;

    float* out0 = (float*)d_out;     // 512*6
    float* pos  = out0 + NG * NC;    // 512*128
    float* gemb = pos + NG * HD;     // 512*128
    float* pen  = gemb + NG * HD;    // 1

    hipMemsetAsync(ws + O, 0, 408704, stream);  // cnt+adj+csum

    // fused prep: cvt | weight transposes | octant count
    k_prep<<<7530, 256, 0, stream>>>(x, xb, W1l, W1r, W2l, W2r, Wc1, w1lt, dst, cnt);
    // hierarchical scan: cnt -> row_off
    k_scan1<<<391, 256, 0, stream>>>(cnt, excl, bsum, NN);
    k_scan2<<<1, 512, 0, stream>>>(bsum, 391);
    k_scan3<<<391, 256, 0, stream>>>(excl, bsum, row_off, NN);
    // octant fill (consumes cnt via count-down)
    k_fill<<<960, 256, 0, stream>>>(src, dst, row_off, cnt, csr);

    const int GEMM_GRID = (NN + 127) / 128;  // 782
    // Layer 1: h1 = relu(mean@W1l + xb@W1r + b1l) -> bufB
    k_gather_b<<<NN / 4, 256, 0, stream>>>(xb, row_off, csr, bufA);
    mfma_dual<<<GEMM_GRID, 256, 0, stream>>>(bufA, w1lt, xb, w1rt, b1l, bufB, NN);
    // Layer 2: h2 = relu(mean@W2l + h1@W2r + b2l) -> xb
    k_gather_b<<<NN / 4, 256, 0, stream>>>(bufB, row_off, csr, bufA);
    mfma_dual<<<GEMM_GRID, 256, 0, stream>>>(bufA, w2lt, bufB, w2rt, b2l, xb, NN);
    // fused: a = softmax(tanh(h2@Wc1+bc1)@Wc2 + bc2)
    mfma_attn<<<GEMM_GRID, 256, 0, stream>>>(xb, wc1t, bc1, Wc2, bc2, a2, NN);
    // pos + colsum fused
    k_pos<<<NG, 512, 0, stream>>>(xb, a2, batch, pos, csum);
    // graph_emb
    k_gemb<<<NG * HD / 256, 256, 0, stream>>>(csum, gemb);
    // new_adj + penalty
    k_adj<<<120, 256, 0, stream>>>(src, dst, batch, a2, adj);
    k_penalty<<<1, 512, 0, stream>>>(adj, pen);
    // head
    gemm_head<<<NG / 32, 256, 0, stream>>>(pos, Wl1, bl1, zbuf, NG);
    k_head<<<2, 256, 0, stream>>>(zbuf, Wl2, bl2, out0);
}

// Round 9
// 307.187 us; speedup vs baseline: 1.5248x; 1.0286x over previous
//
#include <hip/hip_runtime.h>

#define NN 100000
#define NE 640000
#define HD 128
#define NG 512
#define NC 6
#define EPSV 1e-5f
#define OCT 12500   // NN/8 per dst-octant

typedef __bf16 bf16_t;
typedef bf16_t bf16x8 __attribute__((ext_vector_type(8)));
typedef float f32x4 __attribute__((ext_vector_type(4)));

__device__ __forceinline__ float b2f(unsigned int u16) {
    return __builtin_bit_cast(float, u16 << 16);
}
__device__ __forceinline__ unsigned short f2b(float f) {
    unsigned int u = __builtin_bit_cast(unsigned int, f);
    unsigned int r = (u + 0x7fffu + ((u >> 16) & 1u)) >> 16;
    return (unsigned short)r;
}

// ---------------- fused prep: octant count FIRST | x->bf16 cvt | weight transposes ----------------
// blocks [0,960): count (XCD-local octants, dispatched first so it overlaps cvt);
// [960,7210): cvt; [7210,7530): prepw
__global__ __launch_bounds__(256) void k_prep(
    const float* __restrict__ x, unsigned short* __restrict__ xb,
    const float* __restrict__ Wa, const float* __restrict__ Wb,
    const float* __restrict__ Wc, const float* __restrict__ Wd,
    const float* __restrict__ We, unsigned short* __restrict__ Wt,
    const int* __restrict__ dst, int* __restrict__ cnt)
{
    int bid = blockIdx.x;
    if (bid < 960) {
        int oct = bid & 7;            // consistent XCD per octant
        int widx = bid >> 3;          // 0..119
        int lo = oct * OCT, hi = lo + OCT;
        for (int e = widx * 256 + threadIdx.x; e < NE; e += 120 * 256) {
            int d = dst[e];
            if (d >= lo && d < hi) atomicAdd(&cnt[d], 1);
        }
    } else if (bid < 7210) {
        int i = (bid - 960) * 256 + threadIdx.x;  // < 1,600,000
        float4 v0 = reinterpret_cast<const float4*>(x)[i * 2];
        float4 v1 = reinterpret_cast<const float4*>(x)[i * 2 + 1];
        unsigned short u[8] = {f2b(v0.x), f2b(v0.y), f2b(v0.z), f2b(v0.w),
                               f2b(v1.x), f2b(v1.y), f2b(v1.z), f2b(v1.w)};
        reinterpret_cast<uint4*>(xb)[i] = *reinterpret_cast<uint4*>(u);
    } else {
        int i = (bid - 7210) * 256 + threadIdx.x;  // < 81920
        int w = i >> 14, r = i & 16383;
        int k = r >> 7, n = r & 127;
        const float* W = (w == 0) ? Wa : (w == 1) ? Wb : (w == 2) ? Wc : (w == 3) ? Wd : We;
        Wt[w * 16384 + n * HD + k] = f2b(W[k * HD + n]);
    }
}

// ---------------- hierarchical scan (3 kernels, parallel) ----------------
__global__ void k_scan1(const int* __restrict__ cnt, int* __restrict__ excl,
                        int* __restrict__ bsum, int n) {
    __shared__ int sh[256];
    int i = blockIdx.x * 256 + threadIdx.x;
    int v = (i < n) ? cnt[i] : 0;
    sh[threadIdx.x] = v;
    __syncthreads();
    for (int off = 1; off < 256; off <<= 1) {
        int t = (threadIdx.x >= off) ? sh[threadIdx.x - off] : 0;
        __syncthreads();
        sh[threadIdx.x] += t;
        __syncthreads();
    }
    if (i < n) excl[i] = sh[threadIdx.x] - v;
    if (threadIdx.x == 255) bsum[blockIdx.x] = sh[255];
}

__global__ void k_scan2(int* bsum, int nb) {
    __shared__ int sh[512];
    int t = threadIdx.x;
    sh[t] = (t < nb) ? bsum[t] : 0;
    __syncthreads();
    for (int off = 1; off < 512; off <<= 1) {
        int v = (t >= off) ? sh[t - off] : 0;
        __syncthreads();
        sh[t] += v;
        __syncthreads();
    }
    if (t < nb) bsum[t] = sh[t];
}

__global__ void k_scan3(const int* __restrict__ excl, const int* __restrict__ bsum,
                        int* __restrict__ row_off, int n) {
    int i = blockIdx.x * 256 + threadIdx.x;
    if (i < n) row_off[i] = excl[i] + (blockIdx.x ? bsum[blockIdx.x - 1] : 0);
    if (i == 0) row_off[n] = NE;
}

// ---------------- octant-partitioned fill (XCD-local csr writes) ----------------
__global__ __launch_bounds__(256) void k_fill(const int* __restrict__ src,
                                              const int* __restrict__ dst,
                                              const int* __restrict__ row_off,
                                              int* __restrict__ cnt,
                                              int* __restrict__ csr) {
    int q = blockIdx.x;      // 0..959
    int oct = q & 7;
    int widx = q >> 3;
    int lo = oct * OCT, hi = lo + OCT;
    for (int e = widx * 256 + threadIdx.x; e < NE; e += 120 * 256) {
        int d = dst[e];
        if (d >= lo && d < hi) {
            int p = atomicSub(&cnt[d], 1);
            csr[row_off[d] + p - 1] = src[e];
        }
    }
}

// ---------------- mean aggregation: 8 neighbors in flight, 16B loads/lane ----------------
__global__ __launch_bounds__(256) void k_gather_b(const unsigned short* __restrict__ X,
                                                  const int* __restrict__ row_off,
                                                  const int* __restrict__ csr,
                                                  unsigned short* __restrict__ out) {
    int node = (blockIdx.x * blockDim.x + threadIdx.x) >> 6;
    int lane = threadIdx.x & 63;
    if (node >= NN) return;
    int beg = row_off[node], end = row_off[node + 1];
    int grp = lane >> 4;
    int sub = lane & 15;
    float accA[8] = {0.f, 0.f, 0.f, 0.f, 0.f, 0.f, 0.f, 0.f};
    float accB[8] = {0.f, 0.f, 0.f, 0.f, 0.f, 0.f, 0.f, 0.f};
    for (int j = beg; j < end; j += 8) {
        int jj0 = j + grp, jj1 = j + 4 + grp;
        bool ok0 = jj0 < end, ok1 = jj1 < end;
        int s0 = csr[ok0 ? jj0 : beg];
        int s1 = csr[ok1 ? jj1 : beg];
        uint4 v0 = *reinterpret_cast<const uint4*>(X + (size_t)s0 * HD + sub * 8);
        uint4 v1 = *reinterpret_cast<const uint4*>(X + (size_t)s1 * HD + sub * 8);
        if (ok0) {
            accA[0] += b2f(v0.x & 0xffffu); accA[1] += b2f(v0.x >> 16);
            accA[2] += b2f(v0.y & 0xffffu); accA[3] += b2f(v0.y >> 16);
            accA[4] += b2f(v0.z & 0xffffu); accA[5] += b2f(v0.z >> 16);
            accA[6] += b2f(v0.w & 0xffffu); accA[7] += b2f(v0.w >> 16);
        }
        if (ok1) {
            accB[0] += b2f(v1.x & 0xffffu); accB[1] += b2f(v1.x >> 16);
            accB[2] += b2f(v1.y & 0xffffu); accB[3] += b2f(v1.y >> 16);
            accB[4] += b2f(v1.z & 0xffffu); accB[5] += b2f(v1.z >> 16);
            accB[6] += b2f(v1.w & 0xffffu); accB[7] += b2f(v1.w >> 16);
        }
    }
#pragma unroll
    for (int k = 0; k < 8; ++k) {
        float a = accA[k] + accB[k];
        a += __shfl_xor(a, 16, 64);
        a += __shfl_xor(a, 32, 64);
        accA[k] = a;
    }
    if (grp == 0) {
        float inv = 1.f / fmaxf((float)(end - beg), 1.f);
        unsigned short u[8];
#pragma unroll
        for (int k = 0; k < 8; ++k) u[k] = f2b(accA[k] * inv);
        *reinterpret_cast<uint4*>(out + (size_t)node * HD + sub * 8) = *reinterpret_cast<uint4*>(u);
    }
}

// ---------------- MFMA dual-source GEMM, LDS-staged weights, 2-phase ----------------
__global__ __launch_bounds__(256) void mfma_dual(
    const unsigned short* __restrict__ A1, const unsigned short* __restrict__ W1t,
    const unsigned short* __restrict__ A2, const unsigned short* __restrict__ W2t,
    const float* __restrict__ bias, unsigned short* __restrict__ out, int M)
{
    __shared__ uint4 wlds[2048];  // 32 KB
    const int wid = threadIdx.x >> 6;
    const int lane = threadIdx.x & 63;
    const int lrow = lane & 15;
    const int lkg = lane >> 4;
    const int r0 = blockIdx.x * 128 + wid * 32;

    bf16x8 a[2][2][4];
#pragma unroll
    for (int s = 0; s < 2; ++s) {
        const unsigned short* Ap = s ? A2 : A1;
#pragma unroll
        for (int g = 0; g < 2; ++g) {
            int row = r0 + g * 16 + lrow;
            row = row < M ? row : M - 1;
            const unsigned short* p = Ap + (size_t)row * HD + lkg * 8;
#pragma unroll
            for (int ks = 0; ks < 4; ++ks)
                a[s][g][ks] = *reinterpret_cast<const bf16x8*>(p + ks * 32);
        }
    }

    f32x4 acc[2][8];
#pragma unroll
    for (int t = 0; t < 8; ++t) {
        float b = bias[t * 16 + lrow];
        acc[0][t] = (f32x4){b, b, b, b};
        acc[1][t] = (f32x4){b, b, b, b};
    }

    const char* ldsb = (const char*)wlds;
#pragma unroll
    for (int s = 0; s < 2; ++s) {
        const uint4* g4 = reinterpret_cast<const uint4*>(s ? W2t : W1t);
        if (s) __syncthreads();
        for (int i = threadIdx.x; i < 2048; i += 256) {
            int di = i ^ ((i >> 4) & 7);
            wlds[di] = g4[i];
        }
        __syncthreads();
#pragma unroll
        for (int ks = 0; ks < 4; ++ks) {
#pragma unroll
            for (int t = 0; t < 8; ++t) {
                int off = (lrow * 256 + lkg * 16 + t * 4096 + ks * 64) ^ ((lrow & 7) << 4);
                bf16x8 b = *reinterpret_cast<const bf16x8*>(ldsb + off);
                acc[0][t] = __builtin_amdgcn_mfma_f32_16x16x32_bf16(a[s][0][ks], b, acc[0][t], 0, 0, 0);
                acc[1][t] = __builtin_amdgcn_mfma_f32_16x16x32_bf16(a[s][1][ks], b, acc[1][t], 0, 0, 0);
            }
        }
    }

#pragma unroll
    for (int g = 0; g < 2; ++g)
#pragma unroll
        for (int t = 0; t < 8; ++t)
#pragma unroll
            for (int r = 0; r < 4; ++r) {
                int row = r0 + g * 16 + lkg * 4 + r;
                if (row < M) {
                    float v = fmaxf(acc[g][t][r], 0.f);
                    out[(size_t)row * HD + t * 16 + lrow] = f2b(v);
                }
            }
}

// ---------------- fused: a2 = softmax(tanh(h@Wc1+bc1) @ Wc2 + bc2), LDS weights ----------------
__global__ __launch_bounds__(256) void mfma_attn(
    const unsigned short* __restrict__ A1, const unsigned short* __restrict__ W1t,
    const float* __restrict__ bias, const float* __restrict__ Wc2,
    const float* __restrict__ bc2, float* __restrict__ a2, int M)
{
    __shared__ uint4 wlds[2048];
    const int wid = threadIdx.x >> 6;
    const int lane = threadIdx.x & 63;
    const int lrow = lane & 15;
    const int lkg = lane >> 4;
    const int r0 = blockIdx.x * 128 + wid * 32;

    bf16x8 a[2][4];
#pragma unroll
    for (int g = 0; g < 2; ++g) {
        int row = r0 + g * 16 + lrow;
        row = row < M ? row : M - 1;
        const unsigned short* p = A1 + (size_t)row * HD + lkg * 8;
#pragma unroll
        for (int ks = 0; ks < 4; ++ks)
            a[g][ks] = *reinterpret_cast<const bf16x8*>(p + ks * 32);
    }

    f32x4 acc[2][8];
#pragma unroll
    for (int t = 0; t < 8; ++t) {
        float b = bias[t * 16 + lrow];
        acc[0][t] = (f32x4){b, b, b, b};
        acc[1][t] = (f32x4){b, b, b, b};
    }

    const uint4* g4 = reinterpret_cast<const uint4*>(W1t);
    for (int i = threadIdx.x; i < 2048; i += 256) {
        int di = i ^ ((i >> 4) & 7);
        wlds[di] = g4[i];
    }
    __syncthreads();

    const char* ldsb = (const char*)wlds;
#pragma unroll
    for (int ks = 0; ks < 4; ++ks) {
#pragma unroll
        for (int t = 0; t < 8; ++t) {
            int off = (lrow * 256 + lkg * 16 + t * 4096 + ks * 64) ^ ((lrow & 7) << 4);
            bf16x8 b = *reinterpret_cast<const bf16x8*>(ldsb + off);
            acc[0][t] = __builtin_amdgcn_mfma_f32_16x16x32_bf16(a[0][ks], b, acc[0][t], 0, 0, 0);
            acc[1][t] = __builtin_amdgcn_mfma_f32_16x16x32_bf16(a[1][ks], b, acc[1][t], 0, 0, 0);
        }
    }

    float p0[2][4] = {{0.f, 0.f, 0.f, 0.f}, {0.f, 0.f, 0.f, 0.f}};
    float p1[2][4] = {{0.f, 0.f, 0.f, 0.f}, {0.f, 0.f, 0.f, 0.f}};
#pragma unroll
    for (int t = 0; t < 8; ++t) {
        float2 wv = reinterpret_cast<const float2*>(Wc2)[t * 16 + lrow];
#pragma unroll
        for (int g = 0; g < 2; ++g)
#pragma unroll
            for (int r = 0; r < 4; ++r) {
                float tv = tanhf(acc[g][t][r]);
                p0[g][r] = fmaf(tv, wv.x, p0[g][r]);
                p1[g][r] = fmaf(tv, wv.y, p1[g][r]);
            }
    }
#pragma unroll
    for (int off = 1; off < 16; off <<= 1) {
#pragma unroll
        for (int g = 0; g < 2; ++g)
#pragma unroll
            for (int r = 0; r < 4; ++r) {
                p0[g][r] += __shfl_xor(p0[g][r], off, 64);
                p1[g][r] += __shfl_xor(p1[g][r], off, 64);
            }
    }
    if (lrow == 0) {
        float B0 = bc2[0], B1 = bc2[1];
#pragma unroll
        for (int g = 0; g < 2; ++g)
#pragma unroll
            for (int r = 0; r < 4; ++r) {
                int row = r0 + g * 16 + lkg * 4 + r;
                if (row < M) {
                    float u0 = p0[g][r] + B0, u1 = p1[g][r] + B1;
                    float m = fmaxf(u0, u1);
                    float e0 = expf(u0 - m), e1 = expf(u1 - m);
                    float inv = 1.f / (e0 + e1);
                    reinterpret_cast<float2*>(a2)[row] = (float2){e0 * inv, e1 * inv};
                }
            }
    }
}

// ---------------- pos + colsum fused: 16 waves, 2 nodes in flight per wave ----------------
__global__ __launch_bounds__(1024) void k_pos(const unsigned short* __restrict__ h,
                                              const float* __restrict__ a2,
                                              const int* __restrict__ batch,
                                              float* __restrict__ pos_out,
                                              float* __restrict__ csum) {
    __shared__ float4 sh[16][64];
    int g = blockIdx.x;
    int lo = 0, hi = NN;
    while (lo < hi) { int m = (lo + hi) >> 1; if (batch[m] < g) lo = m + 1; else hi = m; }
    int beg = lo;
    hi = NN;
    while (lo < hi) { int m = (lo + hi) >> 1; if (batch[m] < g + 1) lo = m + 1; else hi = m; }
    int end = lo;
    int grp = threadIdx.x >> 6;   // 0..15
    int lane = threadIdx.x & 63;
    float4 acc = {0.f, 0.f, 0.f, 0.f};
    for (int i = beg + grp * 2; i < end; i += 32) {
        int i1 = i + 1;
        bool ok1 = i1 < end;
        float a0 = a2[i * 2];
        unsigned int v0 = *reinterpret_cast<const unsigned int*>(h + (size_t)i * HD + lane * 2);
        float a1 = ok1 ? a2[i1 * 2] : 0.f;
        unsigned int v1 = ok1 ? *reinterpret_cast<const unsigned int*>(h + (size_t)i1 * HD + lane * 2) : 0u;
        float f0 = b2f(v0 & 0xffffu), f1 = b2f(v0 >> 16);
        float g0 = b2f(v1 & 0xffffu), g1 = b2f(v1 >> 16);
        acc.x = fmaf(a0, f0, fmaf(a1, g0, acc.x));
        acc.y = fmaf(a0, f1, fmaf(a1, g1, acc.y));
        acc.z += f0 + g0;
        acc.w += f1 + g1;
    }
    sh[grp][lane] = acc;
    __syncthreads();
    if (threadIdx.x < 64) {
        float4 s = sh[0][lane];
#pragma unroll
        for (int k = 1; k < 16; ++k) {
            float4 t = sh[k][lane];
            s.x += t.x; s.y += t.y; s.z += t.z; s.w += t.w;
        }
        reinterpret_cast<float2*>(pos_out)[g * 64 + lane] = (float2){s.x, s.y};
        atomicAdd(&csum[lane * 2], s.z);
        atomicAdd(&csum[lane * 2 + 1], s.w);
    }
}

__global__ void k_gemb(const float* __restrict__ csum, float* __restrict__ out) {
    int i = blockIdx.x * 256 + threadIdx.x;  // 65536
    out[i] = csum[i & 127] * (1.f / (float)NN);
}

// ---------------- new_adj accumulation: LDS-staged atomics ----------------
__global__ __launch_bounds__(256) void k_adj(const int* __restrict__ src, const int* __restrict__ dst,
                                             const int* __restrict__ batch, const float* __restrict__ a2,
                                             float* __restrict__ adj) {
    __shared__ float sh[NG * 4];  // 8 KB
    for (int i = threadIdx.x; i < NG * 4; i += 256) sh[i] = 0.f;
    __syncthreads();
    for (int e = blockIdx.x * 256 + threadIdx.x; e < NE; e += gridDim.x * 256) {
        int s = src[e], d = dst[e];
        int bs = batch[s], bd = batch[d];
        if (bs != bd) continue;
        float a0s = a2[2 * s], a1s = a2[2 * s + 1];
        float a0d = a2[2 * d], a1d = a2[2 * d + 1];
        float* A = sh + bs * 4;
        atomicAdd(A + 0, a0s * a0d);
        atomicAdd(A + 1, a0s * a1d);
        atomicAdd(A + 2, a1s * a0d);
        atomicAdd(A + 3, a1s * a1d);
    }
    __syncthreads();
    for (int i = threadIdx.x; i < NG * 4; i += 256) {
        float v = sh[i];
        if (v != 0.f) atomicAdd(&adj[i], v);
    }
}

__global__ void k_penalty(const float* __restrict__ adj, float* __restrict__ out) {
    __shared__ float sh[512];
    int g = threadIdx.x;
    float x0 = adj[g * 4], x1 = adj[g * 4 + 1], x2 = adj[g * 4 + 2], x3 = adj[g * 4 + 3];
    float l0 = fabsf(x0) + fabsf(x1);
    float l1 = fabsf(x2) + fabsf(x3);
    float d0 = x0 / fmaxf(l0, EPSV);
    float d1 = x3 / fmaxf(l1, EPSV);
    sh[g] = 0.5f * ((d0 - 1.f) * (d0 - 1.f) + (d1 - 1.f) * (d1 - 1.f));
    __syncthreads();
    for (int off = 256; off >= 1; off >>= 1) {
        if (g < off) sh[g] += sh[g + off];
        __syncthreads();
    }
    if (g == 0) out[0] = sh[0] * (1.f / (float)NG);
}

// ---------------- fp32 head GEMM (512 rows): out = relu(A@W + b) ----------------
__global__ __launch_bounds__(256) void gemm_head(
    const float* __restrict__ A, const float* __restrict__ W,
    const float* __restrict__ bias, float* __restrict__ out, int M)
{
    const int tid = threadIdx.x;
    const int w = __builtin_amdgcn_readfirstlane(tid >> 6);
    const int lane = tid & 63;
    const int r0 = blockIdx.x * 32 + w * 8;
    if (r0 >= M) return;
    const int c0 = lane, c1 = lane + 64;
    float acc0[8], acc1[8];
    const float b0 = bias[c0], b1 = bias[c1];
#pragma unroll
    for (int r = 0; r < 8; ++r) { acc0[r] = b0; acc1[r] = b1; }
    const float* Ap = A + (size_t)r0 * HD;
    for (int k4 = 0; k4 < HD / 4; ++k4) {
        float4 a[8];
#pragma unroll
        for (int r = 0; r < 8; ++r)
            a[r] = *reinterpret_cast<const float4*>(Ap + r * HD + k4 * 4);
#pragma unroll
        for (int j = 0; j < 4; ++j) {
            const int k = k4 * 4 + j;
            const float w0 = W[k * HD + c0];
            const float w1 = W[k * HD + c1];
#pragma unroll
            for (int r = 0; r < 8; ++r) {
                const float av = (j == 0) ? a[r].x : (j == 1) ? a[r].y
                               : (j == 2) ? a[r].z : a[r].w;
                acc0[r] = fmaf(av, w0, acc0[r]);
                acc1[r] = fmaf(av, w1, acc1[r]);
            }
        }
    }
#pragma unroll
    for (int r = 0; r < 8; ++r) {
        out[(size_t)(r0 + r) * HD + c0] = fmaxf(acc0[r], 0.f);
        out[(size_t)(r0 + r) * HD + c1] = fmaxf(acc1[r], 0.f);
    }
}

// ---------------- final head: logits + log_softmax ----------------
__global__ void k_head(const float* __restrict__ z, const float* __restrict__ Wl2,
                       const float* __restrict__ bl2, float* __restrict__ out0) {
    int g = blockIdx.x * blockDim.x + threadIdx.x;
    if (g >= NG) return;
    float l[NC];
#pragma unroll
    for (int c = 0; c < NC; ++c) l[c] = bl2[c];
    for (int k = 0; k < HD; ++k) {
        float zv = z[(size_t)g * HD + k];
#pragma unroll
        for (int c = 0; c < NC; ++c) l[c] = fmaf(zv, Wl2[k * NC + c], l[c]);
    }
    float m = l[0];
#pragma unroll
    for (int c = 1; c < NC; ++c) m = fmaxf(m, l[c]);
    float sum = 0.f;
#pragma unroll
    for (int c = 0; c < NC; ++c) sum += expf(l[c] - m);
    float lse = m + logf(sum);
#pragma unroll
    for (int c = 0; c < NC; ++c) out0[g * NC + c] = l[c] - lse;
}

extern "C" void kernel_launch(void* const* d_in, const int* in_sizes, int n_in,
                              void* d_out, int out_size, void* d_ws, size_t ws_size,
                              hipStream_t stream) {
    const float* x   = (const float*)d_in[0];
    const int*   ei  = (const int*)d_in[1];
    const int*   src = ei;
    const int*   dst = ei + NE;
    const int*   batch = (const int*)d_in[2];
    const float* W1l = (const float*)d_in[4];
    const float* b1l = (const float*)d_in[5];
    const float* W1r = (const float*)d_in[6];
    const float* W2l = (const float*)d_in[7];
    const float* b2l = (const float*)d_in[8];
    const float* W2r = (const float*)d_in[9];
    const float* Wc1 = (const float*)d_in[10];
    const float* bc1 = (const float*)d_in[11];
    const float* Wc2 = (const float*)d_in[12];
    const float* bc2 = (const float*)d_in[13];
    const float* Wl1 = (const float*)d_in[14];
    const float* bl1 = (const float*)d_in[15];
    const float* Wl2 = (const float*)d_in[16];
    const float* bl2 = (const float*)d_in[17];

    char* ws = (char*)d_ws;
    const size_t BB = (size_t)NN * HD * 2;  // 25,600,000 (bf16 buffer)
    unsigned short* xb   = (unsigned short*)(ws);
    unsigned short* bufA = (unsigned short*)(ws + BB);
    unsigned short* bufB = (unsigned short*)(ws + 2 * BB);
    size_t O = 3 * BB;  // 76,800,000
    // zeroed region (single memset): cnt | adj | csum
    int*   cnt     = (int*)(ws + O);                 // 400000 B
    float* adj     = (float*)(ws + O + 400000);      // 8192 B
    float* csum    = (float*)(ws + O + 408192);      // 512 B
    // non-zeroed scratch
    int*   row_off = (int*)(ws + O + 408704);        // 400064 B
    int*   excl    = (int*)(ws + O + 808768);        // 400000 B
    int*   bsum    = (int*)(ws + O + 1208768);       // 4096 B
    int*   csr     = (int*)(ws + O + 1212864);       // 2560000 B
    float* a2      = (float*)(ws + O + 3772864);     // 800000 B
    float* zbuf    = (float*)(ws + O + 4572864);     // 262144 B
    unsigned short* w1lt = (unsigned short*)(ws + O + 4835008);  // 5*32768 B
    unsigned short* w1rt = w1lt + 16384;
    unsigned short* w2lt = w1rt + 16384;
    unsigned short* w2rt = w2lt + 16384;
    unsigned short* wc1t = w2rt + 16384;

    float* out0 = (float*)d_out;     // 512*6
    float* pos  = out0 + NG * NC;    // 512*128
    float* gemb = pos + NG * HD;     // 512*128
    float* pen  = gemb + NG * HD;    // 1

    hipMemsetAsync(ws + O, 0, 408704, stream);  // cnt+adj+csum

    // fused prep: count (first, overlaps) | cvt | weight transposes
    k_prep<<<7530, 256, 0, stream>>>(x, xb, W1l, W1r, W2l, W2r, Wc1, w1lt, dst, cnt);
    // hierarchical scan: cnt -> row_off
    k_scan1<<<391, 256, 0, stream>>>(cnt, excl, bsum, NN);
    k_scan2<<<1, 512, 0, stream>>>(bsum, 391);
    k_scan3<<<391, 256, 0, stream>>>(excl, bsum, row_off, NN);
    // octant fill (consumes cnt via count-down)
    k_fill<<<960, 256, 0, stream>>>(src, dst, row_off, cnt, csr);

    const int GEMM_GRID = (NN + 127) / 128;  // 782
    // Layer 1: h1 = relu(mean@W1l + xb@W1r + b1l) -> bufB
    k_gather_b<<<NN / 4, 256, 0, stream>>>(xb, row_off, csr, bufA);
    mfma_dual<<<GEMM_GRID, 256, 0, stream>>>(bufA, w1lt, xb, w1rt, b1l, bufB, NN);
    // Layer 2: h2 = relu(mean@W2l + h1@W2r + b2l) -> xb
    k_gather_b<<<NN / 4, 256, 0, stream>>>(bufB, row_off, csr, bufA);
    mfma_dual<<<GEMM_GRID, 256, 0, stream>>>(bufA, w2lt, bufB, w2rt, b2l, xb, NN);
    // fused: a = softmax(tanh(h2@Wc1+bc1)@Wc2 + bc2)
    mfma_attn<<<GEMM_GRID, 256, 0, stream>>>(xb, wc1t, bc1, Wc2, bc2, a2, NN);
    // pos + colsum fused (16 waves, 2 nodes in flight per wave)
    k_pos<<<NG, 1024, 0, stream>>>(xb, a2, batch, pos, csum);
    // graph_emb
    k_gemb<<<NG * HD / 256, 256, 0, stream>>>(csum, gemb);
    // new_adj + penalty
    k_adj<<<120, 256, 0, stream>>>(src, dst, batch, a2, adj);
    k_penalty<<<1, 512, 0, stream>>>(adj, pen);
    // head
    gemm_head<<<NG / 32, 256, 0, stream>>>(pos, Wl1, bl1, zbuf, NG);
    k_head<<<2, 256, 0, stream>>>(zbuf, Wl2, bl2, out0);
}